// Round 3
// baseline (1097.515 us; speedup 1.0000x reference)
//
#include <hip/hip_runtime.h>
#include <hip/hip_bf16.h>
#include <stdint.h>

typedef __hip_bfloat16 bf16;

#define NEG 0.2f
#define LN_EPS 1e-5f

__device__ __forceinline__ float bits2f(unsigned short b) {
    return __uint_as_float((unsigned)b << 16);
}
__device__ __forceinline__ bf16 f2b(float v) { return __float2bfloat16(v); }
__device__ __forceinline__ float b2f(bf16 v) { return __bfloat162float(v); }
__device__ __forceinline__ float lrelu(float v) { return v > 0.f ? v : NEG * v; }

// monotonic float <-> uint key for atomicMax on floats
__device__ __forceinline__ unsigned fkey(float f) {
    unsigned u = __float_as_uint(f);
    return (u & 0x80000000u) ? ~u : (u | 0x80000000u);
}
__device__ __forceinline__ float kinv(unsigned u) {
    if (u == 0u) return INFINITY;  // untouched slot: exp(x-inf)=0, never NaN
    return __uint_as_float((u & 0x80000000u) ? (u & 0x7fffffffu) : ~u);
}

// ---- K0: detect float dtype (flags[0]: 1=bf16) and edge-index storage (flags[1]: 1=int64)
__global__ void detect_kernel(const unsigned* __restrict__ xw, const int* __restrict__ ei,
                              int* __restrict__ flags, int E) {
    if (threadIdx.x != 0 || blockIdx.x != 0) return;
    int sane = 0;
    for (int i = 0; i < 256; ++i) {
        unsigned short lo = (unsigned short)(xw[i] & 0xFFFFu);
        int ex = (lo >> 7) & 0xFF;
        if (lo == 0 || (ex > 100 && ex < 155)) sane++;
    }
    flags[0] = (sane > 200) ? 1 : 0;
    int n = E < 64 ? E : 64;
    int all0 = 1;
    for (int i = 0; i < n; ++i)
        if (ei[2 * i + 1] != 0) { all0 = 0; break; }
    flags[1] = all0;
}

// ---- K0b: convert a float-ish input array to fp32 in ws
__global__ __launch_bounds__(256) void cvt_kernel(const void* __restrict__ src,
                                                  float* __restrict__ dst, int n,
                                                  const int* __restrict__ flags) {
    int i = blockIdx.x * 256 + threadIdx.x;
    if (i >= n) return;
    dst[i] = flags[0] ? bits2f(((const unsigned short*)src)[i])
                      : ((const float*)src)[i];
}

// ---- K1: out[n,col] = bf16(sum_k x[n,k]*W[k,col] + b[col]); cols=512, K=128
__global__ __launch_bounds__(256) void proj_kernel(
    const float* __restrict__ x, const float* __restrict__ W,
    const float* __restrict__ bias, bf16* __restrict__ out, int N,
    const int* __restrict__ flags) {
    __shared__ float xs[8][128];
    int isb = flags[0];
    int r0 = blockIdx.x * 8;
    {
        int i = threadIdx.x;  // 8 rows x 32 groups of 4 channels
        int r = i >> 5, c4 = i & 31;
        int gr = r0 + r;
        float v0 = 0.f, v1 = 0.f, v2 = 0.f, v3 = 0.f;
        if (gr < N) {
            if (isb) {
                ushort4 u = ((const ushort4*)x)[(size_t)gr * 32 + c4];
                v0 = bits2f(u.x); v1 = bits2f(u.y); v2 = bits2f(u.z); v3 = bits2f(u.w);
            } else {
                float4 v = ((const float4*)x)[(size_t)gr * 32 + c4];
                v0 = v.x; v1 = v.y; v2 = v.z; v3 = v.w;
            }
        }
        xs[r][c4 * 4 + 0] = v0; xs[r][c4 * 4 + 1] = v1;
        xs[r][c4 * 4 + 2] = v2; xs[r][c4 * 4 + 3] = v3;
    }
    __syncthreads();
    int colp = threadIdx.x;  // cols 2*colp, 2*colp+1
    float accx[8] = {0.f, 0.f, 0.f, 0.f, 0.f, 0.f, 0.f, 0.f};
    float accy[8] = {0.f, 0.f, 0.f, 0.f, 0.f, 0.f, 0.f, 0.f};
    const float2* W2 = (const float2*)W;
    for (int k = 0; k < 128; ++k) {
        float2 w = W2[(size_t)k * 256 + colp];
#pragma unroll
        for (int r = 0; r < 8; ++r) {
            accx[r] += xs[r][k] * w.x;
            accy[r] += xs[r][k] * w.y;
        }
    }
    float2 bb = ((const float2*)bias)[colp];
#pragma unroll
    for (int r = 0; r < 8; ++r) {
        int gr = r0 + r;
        if (gr < N) {
            unsigned short hx = (unsigned short)(__float_as_uint(accx[r] + bb.x +
                                 ((__float_as_uint(accx[r] + bb.x) >> 16) & 1 ? 0.f : 0.f)) >> 16);
            (void)hx;
            bf16 ox = f2b(accx[r] + bb.x);
            bf16 oy = f2b(accy[r] + bb.y);
            out[(size_t)gr * 512 + 2 * colp] = ox;
            out[(size_t)gr * 512 + 2 * colp + 1] = oy;
        }
    }
}

// ---- K2: per-edge GATv2 score; one wave per edge (4 edges/block)
__global__ __launch_bounds__(256) void edge_alpha_kernel(
    const bf16* __restrict__ xl, const bf16* __restrict__ xr,
    const int* __restrict__ ei, const float* __restrict__ att,
    float* __restrict__ alpha, unsigned* __restrict__ amax,
    const int* __restrict__ flags, int E, int ET, int N) {
    __shared__ float atts[512];
    for (int i = threadIdx.x; i < 512; i += 256) atts[i] = att[i];
    __syncthreads();
    int e = blockIdx.x * 4 + (threadIdx.x >> 6);
    if (e >= ET) return;
    int lane = threadIdx.x & 63;
    int s, d;
    if (e < E) {
        if (flags[1]) { s = ei[2 * (size_t)e]; d = ei[2 * (size_t)E + 2 * (size_t)e]; }
        else          { s = ei[e];             d = ei[(size_t)E + e]; }
    } else { s = e - E; d = s; }
    if ((unsigned)s >= (unsigned)N) s = 0;
    if ((unsigned)d >= (unsigned)N) d = 0;
    const unsigned* pl = (const unsigned*)(xl + (size_t)s * 512);
    const unsigned* pr = (const unsigned*)(xr + (size_t)d * 512);
    float a[4];
#pragma unroll
    for (int h = 0; h < 4; ++h) {
        unsigned lw = pl[h * 64 + lane];
        unsigned rw = pr[h * 64 + lane];
        float l0 = bits2f((unsigned short)(lw & 0xFFFF));
        float l1 = bits2f((unsigned short)(lw >> 16));
        float r0v = bits2f((unsigned short)(rw & 0xFFFF));
        float r1v = bits2f((unsigned short)(rw >> 16));
        float v0 = lrelu(l0 + r0v);
        float v1 = lrelu(l1 + r1v);
        a[h] = v0 * atts[h * 128 + 2 * lane] + v1 * atts[h * 128 + 2 * lane + 1];
    }
#pragma unroll
    for (int off = 32; off > 0; off >>= 1) {
#pragma unroll
        for (int h = 0; h < 4; ++h) a[h] += __shfl_xor(a[h], off);
    }
    if (lane == 0) {
#pragma unroll
        for (int h = 0; h < 4; ++h) {
            alpha[(size_t)e * 4 + h] = a[h];
            atomicMax(&amax[(size_t)d * 4 + h], fkey(a[h]));
        }
    }
}

// ---- K3: ex = exp(alpha - amax[dst]); denom[dst] += ex
__global__ __launch_bounds__(256) void edge_exp_kernel(
    const int* __restrict__ ei, const unsigned* __restrict__ amax,
    float* __restrict__ alpha, float* __restrict__ denom,
    const int* __restrict__ flags, int E, int ET, int N) {
    int i = blockIdx.x * 256 + threadIdx.x;
    if (i >= ET * 4) return;
    int e = i >> 2, h = i & 3;
    int d;
    if (e < E) {
        d = flags[1] ? ei[2 * (size_t)E + 2 * (size_t)e] : ei[(size_t)E + e];
    } else d = e - E;
    if ((unsigned)d >= (unsigned)N) d = 0;
    float am = kinv(amax[(size_t)d * 4 + h]);
    float ex = expf(alpha[i] - am);
    alpha[i] = ex;  // in place
    atomicAdd(&denom[(size_t)d * 4 + h], ex);
}

// ---- K4: accum[dst,c] += 0.25 * sum_h w[h] * xl[src,h,c]
__global__ __launch_bounds__(256) void edge_msg_kernel(
    const bf16* __restrict__ xl, const int* __restrict__ ei,
    const float* __restrict__ ex, const float* __restrict__ denom,
    float* __restrict__ accum, const int* __restrict__ flags,
    int E, int ET, int N) {
    int e = blockIdx.x * 4 + (threadIdx.x >> 6);
    if (e >= ET) return;
    int lane = threadIdx.x & 63;
    int s, d;
    if (e < E) {
        if (flags[1]) { s = ei[2 * (size_t)e]; d = ei[2 * (size_t)E + 2 * (size_t)e]; }
        else          { s = ei[e];             d = ei[(size_t)E + e]; }
    } else { s = e - E; d = s; }
    if ((unsigned)s >= (unsigned)N) s = 0;
    if ((unsigned)d >= (unsigned)N) d = 0;
    float4 exv = ((const float4*)ex)[e];
    float4 dnv = ((const float4*)denom)[d];
    float w[4];
    w[0] = 0.25f * exv.x / (dnv.x + 1e-16f);
    w[1] = 0.25f * exv.y / (dnv.y + 1e-16f);
    w[2] = 0.25f * exv.z / (dnv.z + 1e-16f);
    w[3] = 0.25f * exv.w / (dnv.w + 1e-16f);
    const unsigned* pl = (const unsigned*)(xl + (size_t)s * 512);
    float m0 = 0.f, m1 = 0.f;
#pragma unroll
    for (int h = 0; h < 4; ++h) {
        unsigned lw = pl[h * 64 + lane];
        m0 += bits2f((unsigned short)(lw & 0xFFFF)) * w[h];
        m1 += bits2f((unsigned short)(lw >> 16)) * w[h];
    }
    atomicAdd(&accum[(size_t)d * 128 + 2 * lane], m0);
    atomicAdd(&accum[(size_t)d * 128 + 2 * lane + 1], m1);
}

// ---- K5: h = x + accum + gat_bias; hn = LayerNorm(h); one wave per node
__global__ __launch_bounds__(256) void ln_kernel(
    const float* __restrict__ x, const float* __restrict__ accum,
    const float* __restrict__ gat_bias, const float* __restrict__ ln_g,
    const float* __restrict__ ln_b, float* __restrict__ hn, int N,
    const int* __restrict__ flags) {
    int n = blockIdx.x * 4 + (threadIdx.x >> 6);
    if (n >= N) return;
    int isb = flags[0];
    int lane = threadIdx.x & 63;
    size_t base = (size_t)n * 128;
    float xa = isb ? bits2f(((const unsigned short*)x)[base + lane]) : x[base + lane];
    float xb = isb ? bits2f(((const unsigned short*)x)[base + 64 + lane]) : x[base + 64 + lane];
    float v0 = xa + accum[base + lane] + gat_bias[lane];
    float v1 = xb + accum[base + 64 + lane] + gat_bias[64 + lane];
    float s = v0 + v1;
#pragma unroll
    for (int off = 32; off > 0; off >>= 1) s += __shfl_xor(s, off);
    float mu = s * (1.f / 128.f);
    float d0 = v0 - mu, d1 = v1 - mu;
    float vs = d0 * d0 + d1 * d1;
#pragma unroll
    for (int off = 32; off > 0; off >>= 1) vs += __shfl_xor(vs, off);
    float inv = rsqrtf(vs * (1.f / 128.f) + LN_EPS);
    hn[base + lane] = d0 * inv * ln_g[lane] + ln_b[lane];
    hn[base + 64 + lane] = d1 * inv * ln_g[64 + lane] + ln_b[64 + lane];
}

// ---- K6: mid = lrelu(hn @ W1 + b1); cols=256, K=128
__global__ __launch_bounds__(256) void ffn1_kernel(
    const float* __restrict__ hn, const float* __restrict__ W1,
    const float* __restrict__ b1, float* __restrict__ mid, int N) {
    __shared__ float hs[8][128];
    int r0 = blockIdx.x * 8;
    {
        int i = threadIdx.x;
        int r = i >> 5, c4 = i & 31;
        int gr = r0 + r;
        float4 v = make_float4(0.f, 0.f, 0.f, 0.f);
        if (gr < N) v = ((const float4*)hn)[(size_t)gr * 32 + c4];
        hs[r][c4 * 4 + 0] = v.x; hs[r][c4 * 4 + 1] = v.y;
        hs[r][c4 * 4 + 2] = v.z; hs[r][c4 * 4 + 3] = v.w;
    }
    __syncthreads();
    int col = threadIdx.x;
    float acc[8] = {0.f, 0.f, 0.f, 0.f, 0.f, 0.f, 0.f, 0.f};
    for (int k = 0; k < 128; ++k) {
        float w = W1[(size_t)k * 256 + col];
#pragma unroll
        for (int r = 0; r < 8; ++r) acc[r] += hs[r][k] * w;
    }
    float bv = b1[col];
#pragma unroll
    for (int r = 0; r < 8; ++r) {
        int gr = r0 + r;
        if (gr < N) mid[(size_t)gr * 256 + col] = lrelu(acc[r] + bv);
    }
}

// ---- K7: out = (hn + mid @ W2 + b2), stored as bf16 or fp32 per flags[0]
__global__ __launch_bounds__(256) void ffn2_kernel(
    const float* __restrict__ hn, const float* __restrict__ mid,
    const float* __restrict__ W2, const float* __restrict__ b2v,
    void* __restrict__ outv, int N, const int* __restrict__ flags) {
    __shared__ float ms[8][256];
    int r0 = blockIdx.x * 8;
    for (int i = threadIdx.x; i < 8 * 64; i += 256) {
        int r = i >> 6, c4 = i & 63;
        int gr = r0 + r;
        float4 v = make_float4(0.f, 0.f, 0.f, 0.f);
        if (gr < N) v = ((const float4*)mid)[(size_t)gr * 64 + c4];
        ms[r][c4 * 4 + 0] = v.x; ms[r][c4 * 4 + 1] = v.y;
        ms[r][c4 * 4 + 2] = v.z; ms[r][c4 * 4 + 3] = v.w;
    }
    __syncthreads();
    int isb = flags[0];
    int col = threadIdx.x & 127;
    int rh = threadIdx.x >> 7;
    float acc[4] = {0.f, 0.f, 0.f, 0.f};
    for (int k = 0; k < 256; ++k) {
        float w = W2[(size_t)k * 128 + col];
#pragma unroll
        for (int j = 0; j < 4; ++j) acc[j] += ms[rh + 2 * j][k] * w;
    }
    float bv = b2v[col];
#pragma unroll
    for (int j = 0; j < 4; ++j) {
        int gr = r0 + rh + 2 * j;
        if (gr < N) {
            float val = hn[(size_t)gr * 128 + col] + acc[j] + bv;
            if (isb) ((bf16*)outv)[(size_t)gr * 128 + col] = f2b(val);
            else     ((float*)outv)[(size_t)gr * 128 + col] = val;
        }
    }
}

extern "C" void kernel_launch(void* const* d_in, const int* in_sizes, int n_in,
                              void* d_out, int out_size, void* d_ws, size_t ws_size,
                              hipStream_t stream) {
    const float* x = (const float*)d_in[0];
    const int* ei = (const int*)d_in[1];

    int N = in_sizes[0] / 128;
    int E = in_sizes[1] / 2;
    int ET = E + N;

    // ---- workspace layout (~112 MB total)
    char* base = (char*)d_ws;
    int* flags = (int*)base;            // [0]=bf16 mode, [1]=int64 indices
    size_t off = 256;
    float* wf[12];                      // converted fp32 weights (inputs 2..13)
    for (int a = 0; a < 12; ++a) {
        wf[a] = (float*)(base + off);
        off += ((size_t)in_sizes[a + 2] * 4 + 255) & ~(size_t)255;
    }
    off = (off + ((size_t)1 << 20) - 1) & ~(((size_t)1 << 20) - 1);
    bf16* xl = (bf16*)(base + off);     off += (size_t)N * 512 * 2;   // 51.2 MB
    bf16* xr = (bf16*)(base + off);     off += (size_t)N * 512 * 2;   // 51.2 MB
    float* alpha = (float*)(base + off); off += (size_t)ET * 4 * 4;   // 7.2 MB
    float* denom = (float*)(base + off); off += (size_t)N * 4 * 4;    // 0.8 MB
    unsigned* amax = (unsigned*)(base + off); off += (size_t)N * 4 * 4; // 0.8 MB
    // overlays: xr dead after edge_alpha -> accum (first half) + hn (second half)
    float* accum = (float*)xr;
    float* hn = (float*)((char*)xr + (size_t)N * 512);
    // xl dead after edge_msg -> mid
    float* mid = (float*)xl;

    // zero denom + amax (contiguous)
    hipMemsetAsync(denom, 0, (size_t)N * 32, stream);

    detect_kernel<<<1, 64, 0, stream>>>((const unsigned*)x, ei, flags, E);
    for (int a = 0; a < 12; ++a) {
        int n = in_sizes[a + 2];
        cvt_kernel<<<(n + 255) / 256, 256, 0, stream>>>(d_in[a + 2], wf[a], n, flags);
    }

    int nb8 = (N + 7) / 8;
    proj_kernel<<<nb8, 256, 0, stream>>>(x, wf[0], wf[1], xl, N, flags);
    proj_kernel<<<nb8, 256, 0, stream>>>(x, wf[2], wf[3], xr, N, flags);

    int eb = (ET + 3) / 4;
    edge_alpha_kernel<<<eb, 256, 0, stream>>>(xl, xr, ei, wf[4], alpha, amax, flags, E, ET, N);

    // xr now dead -> zero accum overlay
    hipMemsetAsync(accum, 0, (size_t)N * 512, stream);

    edge_exp_kernel<<<(ET * 4 + 255) / 256, 256, 0, stream>>>(ei, amax, alpha, denom, flags, E, ET, N);
    edge_msg_kernel<<<eb, 256, 0, stream>>>(xl, ei, alpha, denom, accum, flags, E, ET, N);

    ln_kernel<<<(N + 3) / 4, 256, 0, stream>>>(x, accum, wf[5], wf[6], wf[7], hn, N, flags);
    ffn1_kernel<<<nb8, 256, 0, stream>>>(hn, wf[8], wf[9], mid, N);
    ffn2_kernel<<<nb8, 256, 0, stream>>>(hn, mid, wf[10], wf[11], d_out, N, flags);
}

// Round 4
// 708.015 us; speedup vs baseline: 1.5501x; 1.5501x over previous
//
#include <hip/hip_runtime.h>
#include <hip/hip_bf16.h>
#include <stdint.h>

typedef __hip_bfloat16 bf16;

#define NEG 0.2f
#define LN_EPS 1e-5f

__device__ __forceinline__ float bits2f(unsigned b) {  // low 16 bits = bf16
    return __uint_as_float(b << 16);
}
__device__ __forceinline__ float hi2f(unsigned b) {    // high 16 bits = bf16
    return __uint_as_float(b & 0xffff0000u);
}
__device__ __forceinline__ bf16 f2b(float v) { return __float2bfloat16(v); }
__device__ __forceinline__ float lrelu(float v) {
    return fmaxf(v, 0.f) + NEG * fminf(v, 0.f);
}
__device__ __forceinline__ void unpack8(uint4 u, float* v) {
    v[0] = bits2f(u.x); v[1] = hi2f(u.x);
    v[2] = bits2f(u.y); v[3] = hi2f(u.y);
    v[4] = bits2f(u.z); v[5] = hi2f(u.z);
    v[6] = bits2f(u.w); v[7] = hi2f(u.w);
}

// ---- K0: detect float dtype (flags[0]=1 -> bf16) and index width (flags[1]=1 -> int64)
__global__ void detect_kernel(const unsigned* __restrict__ xw, const int* __restrict__ ei,
                              int* __restrict__ flags, int E) {
    int lane = threadIdx.x;  // 64 threads
    int sane = 0;
    for (int k = 0; k < 4; ++k) {
        unsigned short lo = (unsigned short)(xw[k * 64 + lane] & 0xFFFFu);
        int ex = (lo >> 7) & 0xFF;
        if (lo == 0 || (ex > 100 && ex < 155)) sane++;
    }
#pragma unroll
    for (int off = 32; off > 0; off >>= 1) sane += __shfl_xor(sane, off);
    int nchk = E < 64 ? E : 64;
    int bad = (lane < nchk) ? (ei[2 * lane + 1] != 0) : 0;
    unsigned long long bb = __ballot(bad);
    if (lane == 0) {
        flags[0] = (sane > 200) ? 1 : 0;
        flags[1] = (bb == 0ULL) ? 1 : 0;
    }
}

// ---- K0b: convert all 12 weight arrays to fp32 in one launch
struct CvtArgs {
    const void* src[12];
    float* dst[12];
    int n[12];
};
__global__ __launch_bounds__(256) void cvt_all_kernel(CvtArgs a, const int* __restrict__ flags) {
    int seg = blockIdx.y;
    int i = blockIdx.x * 256 + threadIdx.x;
    if (i >= a.n[seg]) return;
    a.dst[seg][i] = flags[0] ? bits2f(((const unsigned short*)a.src[seg])[i])
                             : ((const float*)a.src[seg])[i];
}

// ---- K1: out[n,col] = bf16(sum_k x[n,k]*W[k,col] + b[col]); cols=512, K=128; 16 rows/block
__global__ __launch_bounds__(256) void proj_kernel(
    const void* __restrict__ xv, const float* __restrict__ W,
    const float* __restrict__ bias, bf16* __restrict__ out, int N,
    const int* __restrict__ flags) {
    __shared__ float xs[16][128];
    int isb = flags[0];
    int r0 = blockIdx.x * 16;
    for (int i = threadIdx.x; i < 16 * 32; i += 256) {
        int r = i >> 5, c4 = i & 31;
        int gr = r0 + r;
        float v0 = 0.f, v1 = 0.f, v2 = 0.f, v3 = 0.f;
        if (gr < N) {
            if (isb) {
                ushort4 u = ((const ushort4*)xv)[(size_t)gr * 32 + c4];
                v0 = bits2f(u.x); v1 = bits2f(u.y); v2 = bits2f(u.z); v3 = bits2f(u.w);
            } else {
                float4 v = ((const float4*)xv)[(size_t)gr * 32 + c4];
                v0 = v.x; v1 = v.y; v2 = v.z; v3 = v.w;
            }
        }
        xs[r][c4 * 4 + 0] = v0; xs[r][c4 * 4 + 1] = v1;
        xs[r][c4 * 4 + 2] = v2; xs[r][c4 * 4 + 3] = v3;
    }
    __syncthreads();
    int colp = threadIdx.x;  // cols 2*colp, 2*colp+1
    float accx[16], accy[16];
#pragma unroll
    for (int r = 0; r < 16; ++r) { accx[r] = 0.f; accy[r] = 0.f; }
    const float2* W2 = (const float2*)W;
    for (int k = 0; k < 128; ++k) {
        float2 w = W2[(size_t)k * 256 + colp];
#pragma unroll
        for (int r = 0; r < 16; ++r) {
            accx[r] += xs[r][k] * w.x;
            accy[r] += xs[r][k] * w.y;
        }
    }
    float2 bb = ((const float2*)bias)[colp];
#pragma unroll
    for (int r = 0; r < 16; ++r) {
        int gr = r0 + r;
        if (gr < N) {
            out[(size_t)gr * 512 + 2 * colp] = f2b(accx[r] + bb.x);
            out[(size_t)gr * 512 + 2 * colp + 1] = f2b(accy[r] + bb.y);
        }
    }
}

// ---- K2a: deg[i] = 1 (self-loop)
__global__ __launch_bounds__(256) void initdeg_kernel(int* __restrict__ deg, int N) {
    int i = blockIdx.x * 256 + threadIdx.x;
    if (i < N) deg[i] = 1;
}

// ---- K2b: histogram of dst
__global__ __launch_bounds__(256) void hist_kernel(const int* __restrict__ ei,
                                                   int* __restrict__ deg,
                                                   const int* __restrict__ flags,
                                                   int E, int N) {
    int e = blockIdx.x * 256 + threadIdx.x;
    if (e >= E) return;
    int d = flags[1] ? ei[2 * (size_t)E + 2 * (size_t)e] : ei[(size_t)E + e];
    if ((unsigned)d >= (unsigned)N) d = 0;
    atomicAdd(&deg[d], 1);
}

// ---- K2c: exclusive prefix sum; writes rowptr[0..N] and cursor copy
__global__ __launch_bounds__(1024) void scan_kernel(const int* __restrict__ deg,
                                                    int* __restrict__ rowptr,
                                                    int* __restrict__ cursor, int N) {
    __shared__ int part[1024];
    int t = threadIdx.x;
    int chunk = (N + 1023) >> 10;
    int lo = t * chunk;
    int hi = lo + chunk; if (hi > N) hi = N;
    int s = 0;
    for (int i = lo; i < hi; ++i) s += deg[i];
    part[t] = s;
    __syncthreads();
    for (int off = 1; off < 1024; off <<= 1) {
        int v = (t >= off) ? part[t - off] : 0;
        __syncthreads();
        part[t] += v;
        __syncthreads();
    }
    int base = (t == 0) ? 0 : part[t - 1];
    for (int i = lo; i < hi; ++i) {
        int dv = deg[i];
        rowptr[i] = base;
        cursor[i] = base;
        base += dv;
    }
    if (t == 0) rowptr[N] = part[1023];
}

// ---- K2d: scatter edge sources into CSR order (includes self-loops)
__global__ __launch_bounds__(256) void scatter_kernel(const int* __restrict__ ei,
                                                      int* __restrict__ cursor,
                                                      int* __restrict__ srcs,
                                                      const int* __restrict__ flags,
                                                      int E, int ET, int N) {
    int e = blockIdx.x * 256 + threadIdx.x;
    if (e >= ET) return;
    int s, d;
    if (e < E) {
        if (flags[1]) { s = ei[2 * (size_t)e]; d = ei[2 * (size_t)E + 2 * (size_t)e]; }
        else          { s = ei[e];             d = ei[(size_t)E + e]; }
    } else { s = e - E; d = s; }
    if ((unsigned)s >= (unsigned)N) s = 0;
    if ((unsigned)d >= (unsigned)N) d = 0;
    int pos = atomicAdd(&cursor[d], 1);
    srcs[pos] = s;
}

// ---- K3: fused per-node GATv2 (scores + online softmax + aggregate + head-mean)
//          + residual + LayerNorm. One wave per node. hn written into xr row (in-place).
// Lane layout: h = lane>>4, cg = lane&15 -> channels cg*8 .. cg*8+7 of head h.
__global__ __launch_bounds__(256) void agg_kernel(
    const bf16* __restrict__ xl, bf16* __restrict__ xr,
    const void* __restrict__ xv, const int* __restrict__ rowptr,
    const int* __restrict__ srcs, const float* __restrict__ att,
    const float* __restrict__ gat_bias, const float* __restrict__ ln_g,
    const float* __restrict__ ln_b, int N, const int* __restrict__ flags) {
    int n = blockIdx.x * 4 + (threadIdx.x >> 6);
    if (n >= N) return;
    int lane = threadIdx.x & 63;
    int h = lane >> 4, cg = lane & 15;

    // att fragment for this lane
    float att_f[8];
    {
        const float4* ap = (const float4*)(att + (size_t)h * 128 + cg * 8);
        float4 a0 = ap[0], a1 = ap[1];
        att_f[0] = a0.x; att_f[1] = a0.y; att_f[2] = a0.z; att_f[3] = a0.w;
        att_f[4] = a1.x; att_f[5] = a1.y; att_f[6] = a1.z; att_f[7] = a1.w;
    }
    // xr row for this node (read once)
    float xr_f[8];
    uint4 xw = ((const uint4*)(xr + (size_t)n * 512))[lane];
    unpack8(xw, xr_f);

    float o[8];
#pragma unroll
    for (int j = 0; j < 8; ++j) o[j] = 0.f;
    float m = -INFINITY, lsum = 0.f;

    int beg = rowptr[n], end = rowptr[n + 1];
    const uint4* xlu = (const uint4*)xl;
    for (int i = beg; i < end; ++i) {
        int s = srcs[i];
        uint4 lw = xlu[(size_t)s * 64 + lane];
        float v[8];
        unpack8(lw, v);
        float p = 0.f;
#pragma unroll
        for (int j = 0; j < 8; ++j) {
            float t = lrelu(v[j] + xr_f[j]);
            p = fmaf(t, att_f[j], p);
        }
        // reduce over the 16-lane head group -> full 128-channel dot
        p += __shfl_xor(p, 1); p += __shfl_xor(p, 2);
        p += __shfl_xor(p, 4); p += __shfl_xor(p, 8);
        // online softmax for head h
        float nm = fmaxf(m, p);
        float sc = __expf(m - nm);
        float w = __expf(p - nm);
        lsum = lsum * sc + w;
        m = nm;
#pragma unroll
        for (int j = 0; j < 8; ++j) o[j] = o[j] * sc + w * v[j];
    }
    float inv = 0.25f / lsum;  // per-head normalize + head-mean factor
#pragma unroll
    for (int j = 0; j < 8; ++j) o[j] *= inv;
    // sum across the 4 heads (lanes l, l^16, l^32, l^48)
#pragma unroll
    for (int j = 0; j < 8; ++j) {
        o[j] += __shfl_xor(o[j], 16);
        o[j] += __shfl_xor(o[j], 32);
    }
    // residual input x[n]
    float xf[8];
    if (flags[0]) {
        uint4 u = *((const uint4*)((const unsigned short*)xv + (size_t)n * 128 + cg * 8));
        unpack8(u, xf);
    } else {
        const float4* xp = (const float4*)((const float*)xv + (size_t)n * 128 + cg * 8);
        float4 a0 = xp[0], a1 = xp[1];
        xf[0] = a0.x; xf[1] = a0.y; xf[2] = a0.z; xf[3] = a0.w;
        xf[4] = a1.x; xf[5] = a1.y; xf[6] = a1.z; xf[7] = a1.w;
    }
    float gb[8];
    {
        const float4* gp = (const float4*)(gat_bias + cg * 8);
        float4 a0 = gp[0], a1 = gp[1];
        gb[0] = a0.x; gb[1] = a0.y; gb[2] = a0.z; gb[3] = a0.w;
        gb[4] = a1.x; gb[5] = a1.y; gb[6] = a1.z; gb[7] = a1.w;
    }
    float vl[8];
    float s1 = 0.f;
#pragma unroll
    for (int j = 0; j < 8; ++j) { vl[j] = xf[j] + o[j] + gb[j]; s1 += vl[j]; }
    s1 += __shfl_xor(s1, 1); s1 += __shfl_xor(s1, 2);
    s1 += __shfl_xor(s1, 4); s1 += __shfl_xor(s1, 8);
    float mu = s1 * (1.f / 128.f);
    float s2 = 0.f;
#pragma unroll
    for (int j = 0; j < 8; ++j) { float d = vl[j] - mu; s2 += d * d; }
    s2 += __shfl_xor(s2, 1); s2 += __shfl_xor(s2, 2);
    s2 += __shfl_xor(s2, 4); s2 += __shfl_xor(s2, 8);
    float rinv = rsqrtf(s2 * (1.f / 128.f) + LN_EPS);
    if (h == 0) {  // lanes 0..15 write hn (128 floats) into the xr row slot
        float g[8], bt[8];
        const float4* gp = (const float4*)(ln_g + cg * 8);
        float4 g0 = gp[0], g1 = gp[1];
        g[0] = g0.x; g[1] = g0.y; g[2] = g0.z; g[3] = g0.w;
        g[4] = g1.x; g[5] = g1.y; g[6] = g1.z; g[7] = g1.w;
        const float4* bp = (const float4*)(ln_b + cg * 8);
        float4 b0 = bp[0], b1v = bp[1];
        bt[0] = b0.x; bt[1] = b0.y; bt[2] = b0.z; bt[3] = b0.w;
        bt[4] = b1v.x; bt[5] = b1v.y; bt[6] = b1v.z; bt[7] = b1v.w;
        float hnv[8];
#pragma unroll
        for (int j = 0; j < 8; ++j) hnv[j] = (vl[j] - mu) * rinv * g[j] + bt[j];
        float4* hp = (float4*)(xr + (size_t)n * 512);
        hp[cg * 2] = make_float4(hnv[0], hnv[1], hnv[2], hnv[3]);
        hp[cg * 2 + 1] = make_float4(hnv[4], hnv[5], hnv[6], hnv[7]);
    }
}

// ---- K4: mid = lrelu(hn @ W1 + b1); cols=256, K=128; 16 rows/block
// hn rows live at xrbase + gr*1024 bytes (first 512 B of each xr row).
__global__ __launch_bounds__(256) void ffn1_kernel(
    const char* __restrict__ hnbase, const float* __restrict__ W1,
    const float* __restrict__ b1, float* __restrict__ mid, int N) {
    __shared__ float hs[16][128];
    int r0 = blockIdx.x * 16;
    for (int i = threadIdx.x; i < 16 * 32; i += 256) {
        int r = i >> 5, c4 = i & 31;
        int gr = r0 + r;
        float4 v = make_float4(0.f, 0.f, 0.f, 0.f);
        if (gr < N) v = ((const float4*)(hnbase + (size_t)gr * 1024))[c4];
        hs[r][c4 * 4 + 0] = v.x; hs[r][c4 * 4 + 1] = v.y;
        hs[r][c4 * 4 + 2] = v.z; hs[r][c4 * 4 + 3] = v.w;
    }
    __syncthreads();
    int col = threadIdx.x;
    float acc[16];
#pragma unroll
    for (int r = 0; r < 16; ++r) acc[r] = 0.f;
    for (int k = 0; k < 128; ++k) {
        float w = W1[(size_t)k * 256 + col];
#pragma unroll
        for (int r = 0; r < 16; ++r) acc[r] += hs[r][k] * w;
    }
    float bv = b1[col];
#pragma unroll
    for (int r = 0; r < 16; ++r) {
        int gr = r0 + r;
        if (gr < N) mid[(size_t)gr * 256 + col] = lrelu(acc[r] + bv);
    }
}

// ---- K5: out = (hn + mid @ W2 + b2) as bf16/fp32; cols=128, K=256; 16 rows/block
__global__ __launch_bounds__(256) void ffn2_kernel(
    const char* __restrict__ hnbase, const float* __restrict__ mid,
    const float* __restrict__ W2, const float* __restrict__ b2v,
    void* __restrict__ outv, int N, const int* __restrict__ flags) {
    __shared__ float ms[16][256];
    int r0 = blockIdx.x * 16;
    for (int i = threadIdx.x; i < 16 * 64; i += 256) {
        int r = i >> 6, c4 = i & 63;
        int gr = r0 + r;
        float4 v = make_float4(0.f, 0.f, 0.f, 0.f);
        if (gr < N) v = ((const float4*)(mid + (size_t)gr * 256))[c4];
        ms[r][c4 * 4 + 0] = v.x; ms[r][c4 * 4 + 1] = v.y;
        ms[r][c4 * 4 + 2] = v.z; ms[r][c4 * 4 + 3] = v.w;
    }
    __syncthreads();
    int isb = flags[0];
    int col = threadIdx.x & 127;
    int rh = threadIdx.x >> 7;  // 0 or 1; rows rh, rh+2, ..., rh+14
    float acc[8];
#pragma unroll
    for (int j = 0; j < 8; ++j) acc[j] = 0.f;
    for (int k = 0; k < 256; ++k) {
        float w = W2[(size_t)k * 128 + col];
#pragma unroll
        for (int j = 0; j < 8; ++j) acc[j] += ms[rh + 2 * j][k] * w;
    }
    float bv = b2v[col];
#pragma unroll
    for (int j = 0; j < 8; ++j) {
        int gr = r0 + rh + 2 * j;
        if (gr < N) {
            float hval = ((const float*)(hnbase + (size_t)gr * 1024))[col];
            float val = hval + acc[j] + bv;
            if (isb) ((bf16*)outv)[(size_t)gr * 128 + col] = f2b(val);
            else     ((float*)outv)[(size_t)gr * 128 + col] = val;
        }
    }
}

extern "C" void kernel_launch(void* const* d_in, const int* in_sizes, int n_in,
                              void* d_out, int out_size, void* d_ws, size_t ws_size,
                              hipStream_t stream) {
    const void* x = d_in[0];
    const int* ei = (const int*)d_in[1];

    int N = in_sizes[0] / 128;
    int E = in_sizes[1] / 2;
    int ET = E + N;

    // ---- workspace layout (~105 MB)
    char* base = (char*)d_ws;
    int* flags = (int*)base;  // [0]=bf16 mode, [1]=int64 indices
    size_t off = 256;
    float* wf[12];  // fp32 weights (inputs 2..13)
    for (int a = 0; a < 12; ++a) {
        wf[a] = (float*)(base + off);
        off += ((size_t)in_sizes[a + 2] * 4 + 255) & ~(size_t)255;
    }
    off = (off + 1023) & ~(size_t)1023;
    bf16* xl = (bf16*)(base + off);   off += (size_t)N * 512 * 2;  // 51.2 MB; reused as mid (f32)
    bf16* xr = (bf16*)(base + off);   off += (size_t)N * 512 * 2;  // 51.2 MB; rows reused as hn (f32)
    int* srcs = (int*)(base + off);   off += (size_t)ET * 4;       // 1.8 MB
    int* rowptr = (int*)(base + off); off += (size_t)(N + 1) * 4;
    int* deg = (int*)(base + off);    off += (size_t)N * 4;
    int* cursor = (int*)(base + off); off += (size_t)N * 4;
    float* mid = (float*)xl;            // xl dead after agg
    const char* hnbase = (const char*)xr;  // hn rows at stride 1024 B

    detect_kernel<<<1, 64, 0, stream>>>((const unsigned*)x, ei, flags, E);

    CvtArgs ca;
    for (int a = 0; a < 12; ++a) {
        ca.src[a] = d_in[a + 2];
        ca.dst[a] = wf[a];
        ca.n[a] = in_sizes[a + 2];
    }
    cvt_all_kernel<<<dim3(256, 12), 256, 0, stream>>>(ca, flags);

    int nb16 = (N + 15) / 16;
    proj_kernel<<<nb16, 256, 0, stream>>>(x, wf[0], wf[1], xl, N, flags);
    proj_kernel<<<nb16, 256, 0, stream>>>(x, wf[2], wf[3], xr, N, flags);

    initdeg_kernel<<<(N + 255) / 256, 256, 0, stream>>>(deg, N);
    hist_kernel<<<(E + 255) / 256, 256, 0, stream>>>(ei, deg, flags, E, N);
    scan_kernel<<<1, 1024, 0, stream>>>(deg, rowptr, cursor, N);
    scatter_kernel<<<(ET + 255) / 256, 256, 0, stream>>>(ei, cursor, srcs, flags, E, ET, N);

    agg_kernel<<<(N + 3) / 4, 256, 0, stream>>>(xl, xr, x, rowptr, srcs, wf[4],
                                                wf[5], wf[6], wf[7], N, flags);

    ffn1_kernel<<<nb16, 256, 0, stream>>>(hnbase, wf[8], wf[9], mid, N);
    ffn2_kernel<<<nb16, 256, 0, stream>>>(hnbase, mid, wf[10], wf[11], d_out, N, flags);
}

// Round 5
// 562.663 us; speedup vs baseline: 1.9506x; 1.2583x over previous
//
#include <hip/hip_runtime.h>
#include <hip/hip_bf16.h>
#include <stdint.h>

typedef __hip_bfloat16 bf16;
typedef __attribute__((ext_vector_type(8))) short short8;
typedef __attribute__((ext_vector_type(4))) float f32x4;

#define NEG 0.2f
#define LN_EPS 1e-5f

__device__ __forceinline__ float bits2f(unsigned b) {  // low 16 bits = bf16
    return __uint_as_float(b << 16);
}
__device__ __forceinline__ float hi2f(unsigned b) {    // high 16 bits = bf16
    return __uint_as_float(b & 0xffff0000u);
}
__device__ __forceinline__ unsigned short f2b_bits(float f) {  // RNE f32->bf16 bits
    unsigned u = __float_as_uint(f);
    unsigned r = u + 0x7fffu + ((u >> 16) & 1u);
    return (unsigned short)(r >> 16);
}
__device__ __forceinline__ float lrelu(float v) {
    return fmaxf(v, 0.f) + NEG * fminf(v, 0.f);
}
__device__ __forceinline__ void unpack8(uint4 u, float* v) {
    v[0] = bits2f(u.x); v[1] = hi2f(u.x);
    v[2] = bits2f(u.y); v[3] = hi2f(u.y);
    v[4] = bits2f(u.z); v[5] = hi2f(u.z);
    v[6] = bits2f(u.w); v[7] = hi2f(u.w);
}

union S8 { uint4 u; short8 s; unsigned short us[8]; };

// load 8 contiguous bf16 (A/B fragment) from byte pointer
__device__ __forceinline__ short8 ld8b(const char* p) {
    S8 c; c.u = *(const uint4*)p; return c.s;
}
// load 8 contiguous fp32 and convert to bf16 fragment
__device__ __forceinline__ short8 ld8f(const float* p) {
    float4 a = ((const float4*)p)[0], b = ((const float4*)p)[1];
    S8 c;
    c.us[0] = f2b_bits(a.x); c.us[1] = f2b_bits(a.y);
    c.us[2] = f2b_bits(a.z); c.us[3] = f2b_bits(a.w);
    c.us[4] = f2b_bits(b.x); c.us[5] = f2b_bits(b.y);
    c.us[6] = f2b_bits(b.z); c.us[7] = f2b_bits(b.w);
    return c.s;
}

// ---- K0: detect float dtype (flags[0]=1 -> bf16) and index width (flags[1]=1 -> int64)
__global__ void detect_kernel(const unsigned* __restrict__ xw, const int* __restrict__ ei,
                              int* __restrict__ flags, int E) {
    int lane = threadIdx.x;  // 64 threads
    int sane = 0;
    for (int k = 0; k < 4; ++k) {
        unsigned short lo = (unsigned short)(xw[k * 64 + lane] & 0xFFFFu);
        int ex = (lo >> 7) & 0xFF;
        if (lo == 0 || (ex > 100 && ex < 155)) sane++;
    }
#pragma unroll
    for (int off = 32; off > 0; off >>= 1) sane += __shfl_xor(sane, off);
    int nchk = E < 64 ? E : 64;
    int bad = (lane < nchk) ? (ei[2 * lane + 1] != 0) : 0;
    unsigned long long bb = __ballot(bad);
    if (lane == 0) {
        flags[0] = (sane > 200) ? 1 : 0;
        flags[1] = (bb == 0ULL) ? 1 : 0;
    }
}

// ---- K0b: convert all 12 weight arrays to fp32
struct CvtArgs {
    const void* src[12];
    float* dst[12];
    int n[12];
};
__global__ __launch_bounds__(256) void cvt_all_kernel(CvtArgs a, const int* __restrict__ flags) {
    int seg = blockIdx.y;
    int i = blockIdx.x * 256 + threadIdx.x;
    if (i >= a.n[seg]) return;
    a.dst[seg][i] = flags[0] ? bits2f(((const unsigned short*)a.src[seg])[i])
                             : ((const float*)a.src[seg])[i];
}

// ---- K0c: transpose fp32 K x C -> bf16 C x K (k-contiguous rows for B fragments)
__global__ __launch_bounds__(256) void txp_kernel(const float* __restrict__ src,
                                                  unsigned short* __restrict__ dst,
                                                  int K, int C) {
    int i = blockIdx.x * 256 + threadIdx.x;
    if (i >= K * C) return;
    int c = i / K, k = i - c * K;
    dst[i] = f2b_bits(src[(size_t)k * C + c]);
}

// ================= MFMA GEMM kernels =================
// Fragment layouts (m89/m91-verified):
//   A (16x32): lane holds A[m=lane&15][k=quad*8+j], j=0..7, quad=lane>>4
//   B (32x16): lane holds B[k=quad*8+j][n=lane&15]
//   C/D:       reg r -> row=quad*4+r, col=lane&15
// A row-major (k contig), B supplied as B^T row-major (k contig).

// ---- K1: proj: out[n, 0..511] = bf16(x @ W + b). Wave tile 32x64, block 32x256, grid y=2.
__global__ __launch_bounds__(256) void proj_mfma_kernel(
    const void* __restrict__ xv, const unsigned short* __restrict__ Wt,  // 512 x 128 bf16
    const float* __restrict__ bias, unsigned short* __restrict__ out, int N,
    const int* __restrict__ flags) {
    int isb = flags[0];
    int wid = threadIdx.x >> 6, lane = threadIdx.x & 63;
    int quad = lane >> 4, l16 = lane & 15;
    int m0 = blockIdx.x * 32;
    int n0 = blockIdx.y * 256 + wid * 64;

    int ra = m0 + l16;      if (ra >= N) ra = N - 1;
    int rb = m0 + 16 + l16; if (rb >= N) rb = N - 1;

    f32x4 acc[2][4];
#pragma unroll
    for (int r = 0; r < 2; ++r)
#pragma unroll
        for (int c = 0; c < 4; ++c) acc[r][c] = (f32x4){0.f, 0.f, 0.f, 0.f};

#pragma unroll
    for (int kk = 0; kk < 128; kk += 32) {
        short8 a0, a1;
        if (isb) {
            a0 = ld8b((const char*)xv + ((size_t)ra * 128 + kk + quad * 8) * 2);
            a1 = ld8b((const char*)xv + ((size_t)rb * 128 + kk + quad * 8) * 2);
        } else {
            a0 = ld8f((const float*)xv + (size_t)ra * 128 + kk + quad * 8);
            a1 = ld8f((const float*)xv + (size_t)rb * 128 + kk + quad * 8);
        }
#pragma unroll
        for (int c = 0; c < 4; ++c) {
            short8 b = ld8b((const char*)(Wt + (size_t)(n0 + c * 16 + l16) * 128 + kk + quad * 8));
            acc[0][c] = __builtin_amdgcn_mfma_f32_16x16x32_bf16(a0, b, acc[0][c], 0, 0, 0);
            acc[1][c] = __builtin_amdgcn_mfma_f32_16x16x32_bf16(a1, b, acc[1][c], 0, 0, 0);
        }
    }
#pragma unroll
    for (int c = 0; c < 4; ++c) {
        int col = n0 + c * 16 + l16;
        float bv = bias[col];
#pragma unroll
        for (int r = 0; r < 2; ++r) {
#pragma unroll
            for (int j = 0; j < 4; ++j) {
                int row = m0 + r * 16 + quad * 4 + j;
                if (row < N) out[(size_t)row * 512 + col] = f2b_bits(acc[r][c][j] + bv);
            }
        }
    }
}

// ---- CSR build ----
__global__ __launch_bounds__(256) void initdeg_kernel(int* __restrict__ deg, int N) {
    int i = blockIdx.x * 256 + threadIdx.x;
    if (i < N) deg[i] = 1;
}
__global__ __launch_bounds__(256) void hist_kernel(const int* __restrict__ ei,
                                                   int* __restrict__ deg,
                                                   const int* __restrict__ flags,
                                                   int E, int N) {
    int e = blockIdx.x * 256 + threadIdx.x;
    if (e >= E) return;
    int d = flags[1] ? ei[2 * (size_t)E + 2 * (size_t)e] : ei[(size_t)E + e];
    if ((unsigned)d >= (unsigned)N) d = 0;
    atomicAdd(&deg[d], 1);
}
__global__ __launch_bounds__(1024) void scan_kernel(const int* __restrict__ deg,
                                                    int* __restrict__ rowptr,
                                                    int* __restrict__ cursor, int N) {
    __shared__ int part[1024];
    int t = threadIdx.x;
    int chunk = (N + 1023) >> 10;
    int lo = t * chunk;
    int hi = lo + chunk; if (hi > N) hi = N;
    int s = 0;
    for (int i = lo; i < hi; ++i) s += deg[i];
    part[t] = s;
    __syncthreads();
    for (int off = 1; off < 1024; off <<= 1) {
        int v = (t >= off) ? part[t - off] : 0;
        __syncthreads();
        part[t] += v;
        __syncthreads();
    }
    int base = (t == 0) ? 0 : part[t - 1];
    for (int i = lo; i < hi; ++i) {
        int dv = deg[i];
        rowptr[i] = base;
        cursor[i] = base;
        base += dv;
    }
    if (t == 0) rowptr[N] = part[1023];
}
__global__ __launch_bounds__(256) void scatter_kernel(const int* __restrict__ ei,
                                                      int* __restrict__ cursor,
                                                      int* __restrict__ srcs,
                                                      const int* __restrict__ flags,
                                                      int E, int ET, int N) {
    int e = blockIdx.x * 256 + threadIdx.x;
    if (e >= ET) return;
    int s, d;
    if (e < E) {
        if (flags[1]) { s = ei[2 * (size_t)e]; d = ei[2 * (size_t)E + 2 * (size_t)e]; }
        else          { s = ei[e];             d = ei[(size_t)E + e]; }
    } else { s = e - E; d = s; }
    if ((unsigned)s >= (unsigned)N) s = 0;
    if ((unsigned)d >= (unsigned)N) d = 0;
    int pos = atomicAdd(&cursor[d], 1);
    srcs[pos] = s;
}

// ---- K3: fused per-node GATv2 + residual + LayerNorm. One wave per node.
// Writes hn fp32 (512 B) + hn bf16 (256 B) into the node's xr row (1024 B).
__global__ __launch_bounds__(256) void agg_kernel(
    const bf16* __restrict__ xl, bf16* __restrict__ xr,
    const void* __restrict__ xv, const int* __restrict__ rowptr,
    const int* __restrict__ srcs, const float* __restrict__ att,
    const float* __restrict__ gat_bias, const float* __restrict__ ln_g,
    const float* __restrict__ ln_b, int N, const int* __restrict__ flags) {
    int n = blockIdx.x * 4 + (threadIdx.x >> 6);
    if (n >= N) return;
    int lane = threadIdx.x & 63;
    int h = lane >> 4, cg = lane & 15;

    float att_f[8];
    {
        const float4* ap = (const float4*)(att + (size_t)h * 128 + cg * 8);
        float4 a0 = ap[0], a1 = ap[1];
        att_f[0] = a0.x; att_f[1] = a0.y; att_f[2] = a0.z; att_f[3] = a0.w;
        att_f[4] = a1.x; att_f[5] = a1.y; att_f[6] = a1.z; att_f[7] = a1.w;
    }
    float xr_f[8];
    uint4 xw = ((const uint4*)(xr + (size_t)n * 512))[lane];
    unpack8(xw, xr_f);

    float o[8];
#pragma unroll
    for (int j = 0; j < 8; ++j) o[j] = 0.f;
    float m = -INFINITY, lsum = 0.f;

    int beg = rowptr[n], end = rowptr[n + 1];
    const uint4* xlu = (const uint4*)xl;
    for (int i = beg; i < end; ++i) {
        int s = srcs[i];
        uint4 lw = xlu[(size_t)s * 64 + lane];
        float v[8];
        unpack8(lw, v);
        float p = 0.f;
#pragma unroll
        for (int j = 0; j < 8; ++j) {
            float t = lrelu(v[j] + xr_f[j]);
            p = fmaf(t, att_f[j], p);
        }
        p += __shfl_xor(p, 1); p += __shfl_xor(p, 2);
        p += __shfl_xor(p, 4); p += __shfl_xor(p, 8);
        float nm = fmaxf(m, p);
        float sc = __expf(m - nm);
        float w = __expf(p - nm);
        lsum = lsum * sc + w;
        m = nm;
#pragma unroll
        for (int j = 0; j < 8; ++j) o[j] = o[j] * sc + w * v[j];
    }
    float inv = 0.25f / lsum;
#pragma unroll
    for (int j = 0; j < 8; ++j) o[j] *= inv;
#pragma unroll
    for (int j = 0; j < 8; ++j) {
        o[j] += __shfl_xor(o[j], 16);
        o[j] += __shfl_xor(o[j], 32);
    }
    float xf[8];
    if (flags[0]) {
        uint4 u = *((const uint4*)((const unsigned short*)xv + (size_t)n * 128 + cg * 8));
        unpack8(u, xf);
    } else {
        const float4* xp = (const float4*)((const float*)xv + (size_t)n * 128 + cg * 8);
        float4 a0 = xp[0], a1 = xp[1];
        xf[0] = a0.x; xf[1] = a0.y; xf[2] = a0.z; xf[3] = a0.w;
        xf[4] = a1.x; xf[5] = a1.y; xf[6] = a1.z; xf[7] = a1.w;
    }
    float gb[8];
    {
        const float4* gp = (const float4*)(gat_bias + cg * 8);
        float4 a0 = gp[0], a1 = gp[1];
        gb[0] = a0.x; gb[1] = a0.y; gb[2] = a0.z; gb[3] = a0.w;
        gb[4] = a1.x; gb[5] = a1.y; gb[6] = a1.z; gb[7] = a1.w;
    }
    float vl[8];
    float s1 = 0.f;
#pragma unroll
    for (int j = 0; j < 8; ++j) { vl[j] = xf[j] + o[j] + gb[j]; s1 += vl[j]; }
    s1 += __shfl_xor(s1, 1); s1 += __shfl_xor(s1, 2);
    s1 += __shfl_xor(s1, 4); s1 += __shfl_xor(s1, 8);
    float mu = s1 * (1.f / 128.f);
    float s2 = 0.f;
#pragma unroll
    for (int j = 0; j < 8; ++j) { float d = vl[j] - mu; s2 += d * d; }
    s2 += __shfl_xor(s2, 1); s2 += __shfl_xor(s2, 2);
    s2 += __shfl_xor(s2, 4); s2 += __shfl_xor(s2, 8);
    float rinv = rsqrtf(s2 * (1.f / 128.f) + LN_EPS);
    if (h == 0) {  // lanes 0..15: write hn f32 (bytes 0..511) + hn bf16 (bytes 512..767)
        float g[8], bt[8];
        const float4* gp = (const float4*)(ln_g + cg * 8);
        float4 g0 = gp[0], g1 = gp[1];
        g[0] = g0.x; g[1] = g0.y; g[2] = g0.z; g[3] = g0.w;
        g[4] = g1.x; g[5] = g1.y; g[6] = g1.z; g[7] = g1.w;
        const float4* bp = (const float4*)(ln_b + cg * 8);
        float4 b0 = bp[0], b1v = bp[1];
        bt[0] = b0.x; bt[1] = b0.y; bt[2] = b0.z; bt[3] = b0.w;
        bt[4] = b1v.x; bt[5] = b1v.y; bt[6] = b1v.z; bt[7] = b1v.w;
        float hnv[8];
#pragma unroll
        for (int j = 0; j < 8; ++j) hnv[j] = (vl[j] - mu) * rinv * g[j] + bt[j];
        char* rowp = (char*)xr + (size_t)n * 1024;
        float4* hp = (float4*)rowp;
        hp[cg * 2] = make_float4(hnv[0], hnv[1], hnv[2], hnv[3]);
        hp[cg * 2 + 1] = make_float4(hnv[4], hnv[5], hnv[6], hnv[7]);
        uint4 pk;
        pk.x = (unsigned)f2b_bits(hnv[0]) | ((unsigned)f2b_bits(hnv[1]) << 16);
        pk.y = (unsigned)f2b_bits(hnv[2]) | ((unsigned)f2b_bits(hnv[3]) << 16);
        pk.z = (unsigned)f2b_bits(hnv[4]) | ((unsigned)f2b_bits(hnv[5]) << 16);
        pk.w = (unsigned)f2b_bits(hnv[6]) | ((unsigned)f2b_bits(hnv[7]) << 16);
        *(uint4*)(rowp + 512 + cg * 16) = pk;
    }
}

// ---- K4: mid = bf16(lrelu(hn @ W1 + b1)); M=N, N=256, K=128. Block 32x256, grid y=1.
__global__ __launch_bounds__(256) void ffn1_mfma_kernel(
    const char* __restrict__ hnrows,  // hn bf16 at rowp*1024 + 512
    const unsigned short* __restrict__ W1t,  // 256 x 128 bf16
    const float* __restrict__ b1, unsigned short* __restrict__ mid, int N) {
    int wid = threadIdx.x >> 6, lane = threadIdx.x & 63;
    int quad = lane >> 4, l16 = lane & 15;
    int m0 = blockIdx.x * 32;
    int n0 = wid * 64;
    int ra = m0 + l16;      if (ra >= N) ra = N - 1;
    int rb = m0 + 16 + l16; if (rb >= N) rb = N - 1;

    f32x4 acc[2][4];
#pragma unroll
    for (int r = 0; r < 2; ++r)
#pragma unroll
        for (int c = 0; c < 4; ++c) acc[r][c] = (f32x4){0.f, 0.f, 0.f, 0.f};

#pragma unroll
    for (int kk = 0; kk < 128; kk += 32) {
        short8 a0 = ld8b(hnrows + (size_t)ra * 1024 + 512 + (kk + quad * 8) * 2);
        short8 a1 = ld8b(hnrows + (size_t)rb * 1024 + 512 + (kk + quad * 8) * 2);
#pragma unroll
        for (int c = 0; c < 4; ++c) {
            short8 b = ld8b((const char*)(W1t + (size_t)(n0 + c * 16 + l16) * 128 + kk + quad * 8));
            acc[0][c] = __builtin_amdgcn_mfma_f32_16x16x32_bf16(a0, b, acc[0][c], 0, 0, 0);
            acc[1][c] = __builtin_amdgcn_mfma_f32_16x16x32_bf16(a1, b, acc[1][c], 0, 0, 0);
        }
    }
#pragma unroll
    for (int c = 0; c < 4; ++c) {
        int col = n0 + c * 16 + l16;
        float bv = b1[col];
#pragma unroll
        for (int r = 0; r < 2; ++r) {
#pragma unroll
            for (int j = 0; j < 4; ++j) {
                int row = m0 + r * 16 + quad * 4 + j;
                if (row < N) mid[(size_t)row * 256 + col] = f2b_bits(lrelu(acc[r][c][j] + bv));
            }
        }
    }
}

// ---- K5: out = hn + mid @ W2 + b2; M=N, N=128, K=256. Block 64x128 (2x2 waves).
__global__ __launch_bounds__(256) void ffn2_mfma_kernel(
    const unsigned short* __restrict__ mid,  // N x 256 bf16
    const char* __restrict__ hnrows,         // hn f32 at rowp*1024
    const unsigned short* __restrict__ W2t,  // 128 x 256 bf16
    const float* __restrict__ b2v, void* __restrict__ outv, int N,
    const int* __restrict__ flags) {
    int wid = threadIdx.x >> 6, lane = threadIdx.x & 63;
    int quad = lane >> 4, l16 = lane & 15;
    int m0 = blockIdx.x * 64 + (wid >> 1) * 32;
    int n0 = (wid & 1) * 64;
    int ra = m0 + l16;      if (ra >= N) ra = N - 1;
    int rb = m0 + 16 + l16; if (rb >= N) rb = N - 1;

    f32x4 acc[2][4];
#pragma unroll
    for (int r = 0; r < 2; ++r)
#pragma unroll
        for (int c = 0; c < 4; ++c) acc[r][c] = (f32x4){0.f, 0.f, 0.f, 0.f};

#pragma unroll
    for (int kk = 0; kk < 256; kk += 32) {
        short8 a0 = ld8b((const char*)(mid + (size_t)ra * 256 + kk + quad * 8));
        short8 a1 = ld8b((const char*)(mid + (size_t)rb * 256 + kk + quad * 8));
#pragma unroll
        for (int c = 0; c < 4; ++c) {
            short8 b = ld8b((const char*)(W2t + (size_t)(n0 + c * 16 + l16) * 256 + kk + quad * 8));
            acc[0][c] = __builtin_amdgcn_mfma_f32_16x16x32_bf16(a0, b, acc[0][c], 0, 0, 0);
            acc[1][c] = __builtin_amdgcn_mfma_f32_16x16x32_bf16(a1, b, acc[1][c], 0, 0, 0);
        }
    }
    int isb = flags[0];
#pragma unroll
    for (int c = 0; c < 4; ++c) {
        int col = n0 + c * 16 + l16;
        float bv = b2v[col];
#pragma unroll
        for (int r = 0; r < 2; ++r) {
#pragma unroll
            for (int j = 0; j < 4; ++j) {
                int row = m0 + r * 16 + quad * 4 + j;
                if (row < N) {
                    float hval = *(const float*)(hnrows + (size_t)row * 1024 + (size_t)col * 4);
                    float val = hval + acc[r][c][j] + bv;
                    if (isb) ((unsigned short*)outv)[(size_t)row * 128 + col] = f2b_bits(val);
                    else     ((float*)outv)[(size_t)row * 128 + col] = val;
                }
            }
        }
    }
}

extern "C" void kernel_launch(void* const* d_in, const int* in_sizes, int n_in,
                              void* d_out, int out_size, void* d_ws, size_t ws_size,
                              hipStream_t stream) {
    const void* x = d_in[0];
    const int* ei = (const int*)d_in[1];

    int N = in_sizes[0] / 128;
    int E = in_sizes[1] / 2;
    int ET = E + N;

    // ---- workspace layout (~107 MB)
    char* base = (char*)d_ws;
    int* flags = (int*)base;  // [0]=bf16 mode, [1]=int64 indices
    size_t off = 256;
    float* wf[12];  // fp32 weights (inputs 2..13)
    for (int a = 0; a < 12; ++a) {
        wf[a] = (float*)(base + off);
        off += ((size_t)in_sizes[a + 2] * 4 + 255) & ~(size_t)255;
    }
    unsigned short* Wlt = (unsigned short*)(base + off); off += 512 * 128 * 2;
    unsigned short* Wrt = (unsigned short*)(base + off); off += 512 * 128 * 2;
    unsigned short* W1t = (unsigned short*)(base + off); off += 256 * 128 * 2;
    unsigned short* W2t = (unsigned short*)(base + off); off += 128 * 256 * 2;
    off = (off + 1023) & ~(size_t)1023;
    bf16* xl = (bf16*)(base + off);   off += (size_t)N * 512 * 2;  // reused as mid (bf16) after agg
    bf16* xr = (bf16*)(base + off);   off += (size_t)N * 512 * 2;  // rows: hn f32 (512B) + hn bf16 (256B)
    int* srcs = (int*)(base + off);   off += (size_t)ET * 4;
    int* rowptr = (int*)(base + off); off += (size_t)(N + 1) * 4;
    int* deg = (int*)(base + off);    off += (size_t)N * 4;
    int* cursor = (int*)(base + off); off += (size_t)N * 4;
    unsigned short* mid = (unsigned short*)xl;
    const char* hnrows = (const char*)xr;

    detect_kernel<<<1, 64, 0, stream>>>((const unsigned*)x, ei, flags, E);

    CvtArgs ca;
    for (int a = 0; a < 12; ++a) {
        ca.src[a] = d_in[a + 2];
        ca.dst[a] = wf[a];
        ca.n[a] = in_sizes[a + 2];
    }
    cvt_all_kernel<<<dim3(256, 12), 256, 0, stream>>>(ca, flags);

    txp_kernel<<<(512 * 128 + 255) / 256, 256, 0, stream>>>(wf[0], Wlt, 128, 512);
    txp_kernel<<<(512 * 128 + 255) / 256, 256, 0, stream>>>(wf[2], Wrt, 128, 512);
    txp_kernel<<<(256 * 128 + 255) / 256, 256, 0, stream>>>(wf[8], W1t, 128, 256);
    txp_kernel<<<(128 * 256 + 255) / 256, 256, 0, stream>>>(wf[10], W2t, 256, 128);

    int gmb = (N + 31) / 32;
    proj_mfma_kernel<<<dim3(gmb, 2), 256, 0, stream>>>(x, Wlt, wf[1], (unsigned short*)xl, N, flags);
    proj_mfma_kernel<<<dim3(gmb, 2), 256, 0, stream>>>(x, Wrt, wf[3], (unsigned short*)xr, N, flags);

    initdeg_kernel<<<(N + 255) / 256, 256, 0, stream>>>(deg, N);
    hist_kernel<<<(E + 255) / 256, 256, 0, stream>>>(ei, deg, flags, E, N);
    scan_kernel<<<1, 1024, 0, stream>>>(deg, rowptr, cursor, N);
    scatter_kernel<<<(ET + 255) / 256, 256, 0, stream>>>(ei, cursor, srcs, flags, E, ET, N);

    agg_kernel<<<(N + 3) / 4, 256, 0, stream>>>(xl, xr, x, rowptr, srcs, wf[4],
                                                wf[5], wf[6], wf[7], N, flags);

    ffn1_mfma_kernel<<<gmb, 256, 0, stream>>>(hnrows, W1t, wf[9], mid, N);
    ffn2_mfma_kernel<<<(N + 63) / 64, 256, 0, stream>>>(mid, hnrows, W2t, wf[11], d_out, N, flags);
}

// Round 6
// 405.401 us; speedup vs baseline: 2.7072x; 1.3879x over previous
//
#include <hip/hip_runtime.h>
#include <hip/hip_bf16.h>
#include <stdint.h>

typedef __hip_bfloat16 bf16;
typedef __attribute__((ext_vector_type(8))) short short8;
typedef __attribute__((ext_vector_type(4))) float f32x4;

#define NEG 0.2f
#define LN_EPS 1e-5f

__device__ __forceinline__ float bits2f(unsigned b) {  // low 16 bits = bf16
    return __uint_as_float(b << 16);
}
__device__ __forceinline__ float hi2f(unsigned b) {    // high 16 bits = bf16
    return __uint_as_float(b & 0xffff0000u);
}
__device__ __forceinline__ unsigned short f2b_bits(float f) {  // RNE f32->bf16 bits
    unsigned u = __float_as_uint(f);
    unsigned r = u + 0x7fffu + ((u >> 16) & 1u);
    return (unsigned short)(r >> 16);
}
__device__ __forceinline__ float lrelu(float v) {
    return fmaxf(v, 0.f) + NEG * fminf(v, 0.f);
}
__device__ __forceinline__ void unpack8(uint4 u, float* v) {
    v[0] = bits2f(u.x); v[1] = hi2f(u.x);
    v[2] = bits2f(u.y); v[3] = hi2f(u.y);
    v[4] = bits2f(u.z); v[5] = hi2f(u.z);
    v[6] = bits2f(u.w); v[7] = hi2f(u.w);
}

union S8 { uint4 u; short8 s; unsigned short us[8]; };
__device__ __forceinline__ short8 ld8b(const char* p) {
    S8 c; c.u = *(const uint4*)p; return c.s;
}
__device__ __forceinline__ short8 ld8f(const float* p) {
    float4 a = ((const float4*)p)[0], b = ((const float4*)p)[1];
    S8 c;
    c.us[0] = f2b_bits(a.x); c.us[1] = f2b_bits(a.y);
    c.us[2] = f2b_bits(a.z); c.us[3] = f2b_bits(a.w);
    c.us[4] = f2b_bits(b.x); c.us[5] = f2b_bits(b.y);
    c.us[6] = f2b_bits(b.z); c.us[7] = f2b_bits(b.w);
    return c.s;
}

// ---- K0: detect float dtype (flags[0]=1 -> bf16) and index width (flags[1]=1 -> int64)
__global__ void detect_kernel(const unsigned* __restrict__ xw, const int* __restrict__ ei,
                              int* __restrict__ flags, int E) {
    int lane = threadIdx.x;  // 64 threads
    int sane = 0;
    for (int k = 0; k < 4; ++k) {
        unsigned short lo = (unsigned short)(xw[k * 64 + lane] & 0xFFFFu);
        int ex = (lo >> 7) & 0xFF;
        if (lo == 0 || (ex > 100 && ex < 155)) sane++;
    }
#pragma unroll
    for (int off = 32; off > 0; off >>= 1) sane += __shfl_xor(sane, off);
    int nchk = E < 64 ? E : 64;
    int bad = (lane < nchk) ? (ei[2 * lane + 1] != 0) : 0;
    unsigned long long bb = __ballot(bad);
    if (lane == 0) {
        flags[0] = (sane > 200) ? 1 : 0;
        flags[1] = (bb == 0ULL) ? 1 : 0;
    }
}

// ---- K1: consolidated prep: weight transposes (raw -> bf16 W^T), small cvt, deg init
struct PrepArgs {
    const void* Wl; const void* Wr; const void* W1; const void* W2;
    const void* ssrc[8];   // b_l, b_r, att, gat_bias, ln_g, ln_b, b1, b2
    unsigned short* Wlt; unsigned short* Wrt; unsigned short* W1t; unsigned short* W2t;
    float* smalls;         // 2304 floats
    int* deg;
    int N;
};
__global__ __launch_bounds__(256) void prep_kernel(PrepArgs a, const int* __restrict__ flags) {
    int isb = flags[0];
    int i = blockIdx.x * 256 + threadIdx.x;
    int seg = blockIdx.y;
    if (seg == 0) {         // Wlt[c*128+k] <- W_l[k*512+c], 512x128
        if (i < 512 * 128) {
            int c = i >> 7, k = i & 127;
            a.Wlt[i] = isb ? ((const unsigned short*)a.Wl)[k * 512 + c]
                           : f2b_bits(((const float*)a.Wl)[k * 512 + c]);
        }
    } else if (seg == 1) {  // Wrt
        if (i < 512 * 128) {
            int c = i >> 7, k = i & 127;
            a.Wrt[i] = isb ? ((const unsigned short*)a.Wr)[k * 512 + c]
                           : f2b_bits(((const float*)a.Wr)[k * 512 + c]);
        }
    } else if (seg == 2) {  // W1t[c*128+k] <- W1[k*256+c], 256x128
        if (i < 256 * 128) {
            int c = i >> 7, k = i & 127;
            a.W1t[i] = isb ? ((const unsigned short*)a.W1)[k * 256 + c]
                           : f2b_bits(((const float*)a.W1)[k * 256 + c]);
        }
    } else if (seg == 3) {  // W2t[c*256+k] <- W2[k*128+c], 128x256
        if (i < 128 * 256) {
            int c = i >> 8, k = i & 255;
            a.W2t[i] = isb ? ((const unsigned short*)a.W2)[k * 128 + c]
                           : f2b_bits(((const float*)a.W2)[k * 128 + c]);
        }
    } else if (seg == 4) {  // deg init (self-loop)
        if (i < a.N) a.deg[i] = 1;
    } else {                // smalls cvt: sizes 512,512,512,128,128,128,256,128
        const int sn[8] = {512, 512, 512, 128, 128, 128, 256, 128};
        int off = 0;
        for (int t = 0; t < 8; ++t) {
            if (i < off + sn[t]) {
                int j = i - off;
                a.smalls[i] = isb ? bits2f(((const unsigned short*)a.ssrc[t])[j])
                                  : ((const float*)a.ssrc[t])[j];
                return;
            }
            off += sn[t];
        }
    }
}

// ================= MFMA GEMM =================
// A (16x32): lane holds A[m=lane&15][k=quad*8+j]; B (32x16): B[k=quad*8+j][n=lane&15]
// C/D: reg j -> row=quad*4+j, col=lane&15.  (m89/m91-verified)

// ---- K2: merged proj: grid.y 0-1 -> xl (Wlt, b_l), 2-3 -> xr (Wrt, b_r)
__global__ __launch_bounds__(256) void proj_mfma_kernel(
    const void* __restrict__ xv, const unsigned short* __restrict__ Wlt,
    const unsigned short* __restrict__ Wrt, const float* __restrict__ smalls,
    unsigned short* __restrict__ xl, unsigned short* __restrict__ xr,
    int N, const int* __restrict__ flags) {
    int isb = flags[0];
    int half = blockIdx.y >> 1;
    const unsigned short* Wt = half ? Wrt : Wlt;
    const float* bias = smalls + (half ? 512 : 0);
    unsigned short* out = half ? xr : xl;
    int wid = threadIdx.x >> 6, lane = threadIdx.x & 63;
    int quad = lane >> 4, l16 = lane & 15;
    int m0 = blockIdx.x * 32;
    int n0 = (blockIdx.y & 1) * 256 + wid * 64;

    int ra = m0 + l16;      if (ra >= N) ra = N - 1;
    int rb = m0 + 16 + l16; if (rb >= N) rb = N - 1;

    f32x4 acc[2][4];
#pragma unroll
    for (int r = 0; r < 2; ++r)
#pragma unroll
        for (int c = 0; c < 4; ++c) acc[r][c] = (f32x4){0.f, 0.f, 0.f, 0.f};

#pragma unroll
    for (int kk = 0; kk < 128; kk += 32) {
        short8 a0, a1;
        if (isb) {
            a0 = ld8b((const char*)xv + ((size_t)ra * 128 + kk + quad * 8) * 2);
            a1 = ld8b((const char*)xv + ((size_t)rb * 128 + kk + quad * 8) * 2);
        } else {
            a0 = ld8f((const float*)xv + (size_t)ra * 128 + kk + quad * 8);
            a1 = ld8f((const float*)xv + (size_t)rb * 128 + kk + quad * 8);
        }
#pragma unroll
        for (int c = 0; c < 4; ++c) {
            short8 b = ld8b((const char*)(Wt + (size_t)(n0 + c * 16 + l16) * 128 + kk + quad * 8));
            acc[0][c] = __builtin_amdgcn_mfma_f32_16x16x32_bf16(a0, b, acc[0][c], 0, 0, 0);
            acc[1][c] = __builtin_amdgcn_mfma_f32_16x16x32_bf16(a1, b, acc[1][c], 0, 0, 0);
        }
    }
#pragma unroll
    for (int c = 0; c < 4; ++c) {
        int col = n0 + c * 16 + l16;
        float bv = bias[col];
#pragma unroll
        for (int r = 0; r < 2; ++r) {
#pragma unroll
            for (int j = 0; j < 4; ++j) {
                int row = m0 + r * 16 + quad * 4 + j;
                if (row < N) out[(size_t)row * 512 + col] = f2b_bits(acc[r][c][j] + bv);
            }
        }
    }
}

// ---- CSR build ----
__global__ __launch_bounds__(256) void hist_kernel(const int* __restrict__ ei,
                                                   int* __restrict__ deg,
                                                   const int* __restrict__ flags,
                                                   int E, int N) {
    int e = blockIdx.x * 256 + threadIdx.x;
    if (e >= E) return;
    int d = flags[1] ? ei[2 * (size_t)E + 2 * (size_t)e] : ei[(size_t)E + e];
    if ((unsigned)d >= (unsigned)N) d = 0;
    atomicAdd(&deg[d], 1);
}

// scanA: part[b] = sum of deg over block b's 256-chunk
__global__ __launch_bounds__(256) void scanA_kernel(const int* __restrict__ deg,
                                                    int* __restrict__ part, int N) {
    int t = threadIdx.x, lane = t & 63, wid = t >> 6;
    int i = blockIdx.x * 256 + t;
    int v = (i < N) ? deg[i] : 0;
#pragma unroll
    for (int off = 32; off > 0; off >>= 1) v += __shfl_xor(v, off);
    __shared__ int ws4[4];
    if (lane == 0) ws4[wid] = v;
    __syncthreads();
    if (t == 0) part[blockIdx.x] = ws4[0] + ws4[1] + ws4[2] + ws4[3];
}

// scanB: in-place exclusive scan of part[0..nb); rowptr[N] = total
__global__ __launch_bounds__(1024) void scanB_kernel(int* __restrict__ part,
                                                     int* __restrict__ rowptr,
                                                     int nb, int N) {
    int t = threadIdx.x, lane = t & 63, wid = t >> 6;
    int v = (t < nb) ? part[t] : 0;
    int x = v;
#pragma unroll
    for (int off = 1; off < 64; off <<= 1) {
        int u = __shfl_up(x, off);
        if (lane >= off) x += u;
    }
    __shared__ int wsum[16];
    if (lane == 63) wsum[wid] = x;
    __syncthreads();
    if (wid == 0 && lane < 16) {
        int y = wsum[lane];
#pragma unroll
        for (int off = 1; off < 16; off <<= 1) {
            int u = __shfl_up(y, off);
            if (lane >= off) y += u;
        }
        wsum[lane] = y;
    }
    __syncthreads();
    int base = (wid > 0) ? wsum[wid - 1] : 0;
    int incl = base + x;
    if (t < nb) part[t] = incl - v;  // exclusive block base
    if (t == nb - 1) rowptr[N] = incl;
}

// scanC: per-chunk exclusive scan + block base -> rowptr, cursor
__global__ __launch_bounds__(256) void scanC_kernel(const int* __restrict__ deg,
                                                    const int* __restrict__ part,
                                                    int* __restrict__ rowptr,
                                                    int* __restrict__ cursor, int N) {
    int t = threadIdx.x, lane = t & 63, wid = t >> 6;
    int i = blockIdx.x * 256 + t;
    int v = (i < N) ? deg[i] : 0;
    int x = v;
#pragma unroll
    for (int off = 1; off < 64; off <<= 1) {
        int u = __shfl_up(x, off);
        if (lane >= off) x += u;
    }
    __shared__ int wsum[4];
    if (lane == 63) wsum[wid] = x;
    __syncthreads();
    int base = part[blockIdx.x];
    for (int w = 0; w < wid; ++w) base += wsum[w];
    int excl = base + x - v;
    if (i < N) { rowptr[i] = excl; cursor[i] = excl; }
}

__global__ __launch_bounds__(256) void scatter_kernel(const int* __restrict__ ei,
                                                      int* __restrict__ cursor,
                                                      int* __restrict__ srcs,
                                                      const int* __restrict__ flags,
                                                      int E, int ET, int N) {
    int e = blockIdx.x * 256 + threadIdx.x;
    if (e >= ET) return;
    int s, d;
    if (e < E) {
        if (flags[1]) { s = ei[2 * (size_t)e]; d = ei[2 * (size_t)E + 2 * (size_t)e]; }
        else          { s = ei[e];             d = ei[(size_t)E + e]; }
    } else { s = e - E; d = s; }
    if ((unsigned)s >= (unsigned)N) s = 0;
    if ((unsigned)d >= (unsigned)N) d = 0;
    int pos = atomicAdd(&cursor[d], 1);
    srcs[pos] = s;
}

// ---- K5: fused per-node GATv2 + residual + LayerNorm. One wave per node.
// Softmax without max-subtraction (shift-invariant; scores O(1), clamp 60 for safety).
// 1-deep software pipeline on the xl row gather.
__global__ __launch_bounds__(256) void agg_kernel(
    const bf16* __restrict__ xl, bf16* __restrict__ xr,
    const void* __restrict__ xv, const int* __restrict__ rowptr,
    const int* __restrict__ srcs, const float* __restrict__ smalls,
    int N, const int* __restrict__ flags) {
    int n = blockIdx.x * 4 + (threadIdx.x >> 6);
    if (n >= N) return;
    int lane = threadIdx.x & 63;
    int h = lane >> 4, cg = lane & 15;
    const float* att = smalls + 1024;
    const float* gat_bias = smalls + 1536;
    const float* ln_g = smalls + 1664;
    const float* ln_b = smalls + 1792;

    float att_f[8];
    {
        const float4* ap = (const float4*)(att + (size_t)h * 128 + cg * 8);
        float4 a0 = ap[0], a1 = ap[1];
        att_f[0] = a0.x; att_f[1] = a0.y; att_f[2] = a0.z; att_f[3] = a0.w;
        att_f[4] = a1.x; att_f[5] = a1.y; att_f[6] = a1.z; att_f[7] = a1.w;
    }
    float xr_f[8];
    uint4 xw = ((const uint4*)(xr + (size_t)n * 512))[lane];
    unpack8(xw, xr_f);

    float o[8];
#pragma unroll
    for (int j = 0; j < 8; ++j) o[j] = 0.f;
    float lsum = 0.f;

    int beg = rowptr[n], end = rowptr[n + 1];
    const uint4* xlu = (const uint4*)xl;
    int sA = srcs[beg];                                // deg >= 1 (self-loop)
    int sB = (beg + 1 < end) ? srcs[beg + 1] : sA;
    uint4 lw = xlu[(size_t)sA * 64 + lane];
    for (int i = beg; i < end; ++i) {
        uint4 cur = lw;
        int snext = sB;
        if (i + 2 < end) sB = srcs[i + 2];
        if (i + 1 < end) lw = xlu[(size_t)snext * 64 + lane];
        float v[8];
        unpack8(cur, v);
        float p = 0.f;
#pragma unroll
        for (int j = 0; j < 8; ++j) {
            float t = lrelu(v[j] + xr_f[j]);
            p = fmaf(t, att_f[j], p);
        }
        p += __shfl_xor(p, 1); p += __shfl_xor(p, 2);
        p += __shfl_xor(p, 4); p += __shfl_xor(p, 8);
        float w = __expf(fminf(p, 60.f));
        lsum += w;
#pragma unroll
        for (int j = 0; j < 8; ++j) o[j] = fmaf(w, v[j], o[j]);
    }
    float inv = 0.25f / lsum;
#pragma unroll
    for (int j = 0; j < 8; ++j) o[j] *= inv;
#pragma unroll
    for (int j = 0; j < 8; ++j) {
        o[j] += __shfl_xor(o[j], 16);
        o[j] += __shfl_xor(o[j], 32);
    }
    float xf[8];
    if (flags[0]) {
        uint4 u = *((const uint4*)((const unsigned short*)xv + (size_t)n * 128 + cg * 8));
        unpack8(u, xf);
    } else {
        const float4* xp = (const float4*)((const float*)xv + (size_t)n * 128 + cg * 8);
        float4 a0 = xp[0], a1 = xp[1];
        xf[0] = a0.x; xf[1] = a0.y; xf[2] = a0.z; xf[3] = a0.w;
        xf[4] = a1.x; xf[5] = a1.y; xf[6] = a1.z; xf[7] = a1.w;
    }
    float gb[8];
    {
        const float4* gp = (const float4*)(gat_bias + cg * 8);
        float4 a0 = gp[0], a1 = gp[1];
        gb[0] = a0.x; gb[1] = a0.y; gb[2] = a0.z; gb[3] = a0.w;
        gb[4] = a1.x; gb[5] = a1.y; gb[6] = a1.z; gb[7] = a1.w;
    }
    float vl[8];
    float s1 = 0.f;
#pragma unroll
    for (int j = 0; j < 8; ++j) { vl[j] = xf[j] + o[j] + gb[j]; s1 += vl[j]; }
    s1 += __shfl_xor(s1, 1); s1 += __shfl_xor(s1, 2);
    s1 += __shfl_xor(s1, 4); s1 += __shfl_xor(s1, 8);
    float mu = s1 * (1.f / 128.f);
    float s2 = 0.f;
#pragma unroll
    for (int j = 0; j < 8; ++j) { float d = vl[j] - mu; s2 += d * d; }
    s2 += __shfl_xor(s2, 1); s2 += __shfl_xor(s2, 2);
    s2 += __shfl_xor(s2, 4); s2 += __shfl_xor(s2, 8);
    float rinv = rsqrtf(s2 * (1.f / 128.f) + LN_EPS);
    if (h == 0) {  // lanes 0..15: hn f32 -> bytes 0..511, hn bf16 -> bytes 512..767
        float g[8], bt[8];
        const float4* gp = (const float4*)(ln_g + cg * 8);
        float4 g0 = gp[0], g1 = gp[1];
        g[0] = g0.x; g[1] = g0.y; g[2] = g0.z; g[3] = g0.w;
        g[4] = g1.x; g[5] = g1.y; g[6] = g1.z; g[7] = g1.w;
        const float4* bp = (const float4*)(ln_b + cg * 8);
        float4 b0 = bp[0], b1v = bp[1];
        bt[0] = b0.x; bt[1] = b0.y; bt[2] = b0.z; bt[3] = b0.w;
        bt[4] = b1v.x; bt[5] = b1v.y; bt[6] = b1v.z; bt[7] = b1v.w;
        float hnv[8];
#pragma unroll
        for (int j = 0; j < 8; ++j) hnv[j] = (vl[j] - mu) * rinv * g[j] + bt[j];
        char* rowp = (char*)xr + (size_t)n * 1024;
        float4* hp = (float4*)rowp;
        hp[cg * 2] = make_float4(hnv[0], hnv[1], hnv[2], hnv[3]);
        hp[cg * 2 + 1] = make_float4(hnv[4], hnv[5], hnv[6], hnv[7]);
        uint4 pk;
        pk.x = (unsigned)f2b_bits(hnv[0]) | ((unsigned)f2b_bits(hnv[1]) << 16);
        pk.y = (unsigned)f2b_bits(hnv[2]) | ((unsigned)f2b_bits(hnv[3]) << 16);
        pk.z = (unsigned)f2b_bits(hnv[4]) | ((unsigned)f2b_bits(hnv[5]) << 16);
        pk.w = (unsigned)f2b_bits(hnv[6]) | ((unsigned)f2b_bits(hnv[7]) << 16);
        *(uint4*)(rowp + 512 + cg * 16) = pk;
    }
}

// ---- K6: mid = bf16(lrelu(hn @ W1 + b1)); N=256 cols, K=128
__global__ __launch_bounds__(256) void ffn1_mfma_kernel(
    const char* __restrict__ hnrows, const unsigned short* __restrict__ W1t,
    const float* __restrict__ smalls, unsigned short* __restrict__ mid, int N) {
    const float* b1 = smalls + 1920;
    int wid = threadIdx.x >> 6, lane = threadIdx.x & 63;
    int quad = lane >> 4, l16 = lane & 15;
    int m0 = blockIdx.x * 32;
    int n0 = wid * 64;
    int ra = m0 + l16;      if (ra >= N) ra = N - 1;
    int rb = m0 + 16 + l16; if (rb >= N) rb = N - 1;

    f32x4 acc[2][4];
#pragma unroll
    for (int r = 0; r < 2; ++r)
#pragma unroll
        for (int c = 0; c < 4; ++c) acc[r][c] = (f32x4){0.f, 0.f, 0.f, 0.f};

#pragma unroll
    for (int kk = 0; kk < 128; kk += 32) {
        short8 a0 = ld8b(hnrows + (size_t)ra * 1024 + 512 + (kk + quad * 8) * 2);
        short8 a1 = ld8b(hnrows + (size_t)rb * 1024 + 512 + (kk + quad * 8) * 2);
#pragma unroll
        for (int c = 0; c < 4; ++c) {
            short8 b = ld8b((const char*)(W1t + (size_t)(n0 + c * 16 + l16) * 128 + kk + quad * 8));
            acc[0][c] = __builtin_amdgcn_mfma_f32_16x16x32_bf16(a0, b, acc[0][c], 0, 0, 0);
            acc[1][c] = __builtin_amdgcn_mfma_f32_16x16x32_bf16(a1, b, acc[1][c], 0, 0, 0);
        }
    }
#pragma unroll
    for (int c = 0; c < 4; ++c) {
        int col = n0 + c * 16 + l16;
        float bv = b1[col];
#pragma unroll
        for (int r = 0; r < 2; ++r) {
#pragma unroll
            for (int j = 0; j < 4; ++j) {
                int row = m0 + r * 16 + quad * 4 + j;
                if (row < N) mid[(size_t)row * 256 + col] = f2b_bits(lrelu(acc[r][c][j] + bv));
            }
        }
    }
}

// ---- K7: out = hn + mid @ W2 + b2; N=128 cols, K=256
__global__ __launch_bounds__(256) void ffn2_mfma_kernel(
    const unsigned short* __restrict__ mid, const char* __restrict__ hnrows,
    const unsigned short* __restrict__ W2t, const float* __restrict__ smalls,
    void* __restrict__ outv, int N, const int* __restrict__ flags) {
    const float* b2v = smalls + 2176;
    int wid = threadIdx.x >> 6, lane = threadIdx.x & 63;
    int quad = lane >> 4, l16 = lane & 15;
    int m0 = blockIdx.x * 64 + (wid >> 1) * 32;
    int n0 = (wid & 1) * 64;
    int ra = m0 + l16;      if (ra >= N) ra = N - 1;
    int rb = m0 + 16 + l16; if (rb >= N) rb = N - 1;

    f32x4 acc[2][4];
#pragma unroll
    for (int r = 0; r < 2; ++r)
#pragma unroll
        for (int c = 0; c < 4; ++c) acc[r][c] = (f32x4){0.f, 0.f, 0.f, 0.f};

#pragma unroll
    for (int kk = 0; kk < 256; kk += 32) {
        short8 a0 = ld8b((const char*)(mid + (size_t)ra * 256 + kk + quad * 8));
        short8 a1 = ld8b((const char*)(mid + (size_t)rb * 256 + kk + quad * 8));
#pragma unroll
        for (int c = 0; c < 4; ++c) {
            short8 b = ld8b((const char*)(W2t + (size_t)(n0 + c * 16 + l16) * 256 + kk + quad * 8));
            acc[0][c] = __builtin_amdgcn_mfma_f32_16x16x32_bf16(a0, b, acc[0][c], 0, 0, 0);
            acc[1][c] = __builtin_amdgcn_mfma_f32_16x16x32_bf16(a1, b, acc[1][c], 0, 0, 0);
        }
    }
    int isb = flags[0];
#pragma unroll
    for (int c = 0; c < 4; ++c) {
        int col = n0 + c * 16 + l16;
        float bv = b2v[col];
#pragma unroll
        for (int r = 0; r < 2; ++r) {
#pragma unroll
            for (int j = 0; j < 4; ++j) {
                int row = m0 + r * 16 + quad * 4 + j;
                if (row < N) {
                    float hval = *(const float*)(hnrows + (size_t)row * 1024 + (size_t)col * 4);
                    float val = hval + acc[r][c][j] + bv;
                    if (isb) ((unsigned short*)outv)[(size_t)row * 128 + col] = f2b_bits(val);
                    else     ((float*)outv)[(size_t)row * 128 + col] = val;
                }
            }
        }
    }
}

extern "C" void kernel_launch(void* const* d_in, const int* in_sizes, int n_in,
                              void* d_out, int out_size, void* d_ws, size_t ws_size,
                              hipStream_t stream) {
    const void* x = d_in[0];
    const int* ei = (const int*)d_in[1];

    int N = in_sizes[0] / 128;
    int E = in_sizes[1] / 2;
    int ET = E + N;
    int nb = (N + 255) / 256;

    // ---- workspace layout (~105 MB)
    char* base = (char*)d_ws;
    int* flags = (int*)base;
    size_t off = 256;
    float* smalls = (float*)(base + off);               off += 2304 * 4;
    off = (off + 255) & ~(size_t)255;
    unsigned short* Wlt = (unsigned short*)(base + off); off += 512 * 128 * 2;
    unsigned short* Wrt = (unsigned short*)(base + off); off += 512 * 128 * 2;
    unsigned short* W1t = (unsigned short*)(base + off); off += 256 * 128 * 2;
    unsigned short* W2t = (unsigned short*)(base + off); off += 128 * 256 * 2;
    off = (off + 1023) & ~(size_t)1023;
    bf16* xl = (bf16*)(base + off);   off += (size_t)N * 512 * 2;  // -> mid (bf16) after agg
    bf16* xr = (bf16*)(base + off);   off += (size_t)N * 512 * 2;  // rows: hn f32 + hn bf16
    int* srcs = (int*)(base + off);   off += (size_t)ET * 4;
    int* rowptr = (int*)(base + off); off += (size_t)(N + 1) * 4;
    int* deg = (int*)(base + off);    off += (size_t)N * 4;
    int* cursor = (int*)(base + off); off += (size_t)N * 4;
    int* part = (int*)(base + off);   off += (size_t)nb * 4;
    unsigned short* mid = (unsigned short*)xl;
    const char* hnrows = (const char*)xr;

    detect_kernel<<<1, 64, 0, stream>>>((const unsigned*)x, ei, flags, E);

    PrepArgs pa;
    pa.Wl = d_in[2]; pa.Wr = d_in[4]; pa.W1 = d_in[10]; pa.W2 = d_in[12];
    pa.ssrc[0] = d_in[3];  pa.ssrc[1] = d_in[5];  pa.ssrc[2] = d_in[6];
    pa.ssrc[3] = d_in[7];  pa.ssrc[4] = d_in[8];  pa.ssrc[5] = d_in[9];
    pa.ssrc[6] = d_in[11]; pa.ssrc[7] = d_in[13];
    pa.Wlt = Wlt; pa.Wrt = Wrt; pa.W1t = W1t; pa.W2t = W2t;
    pa.smalls = smalls; pa.deg = deg; pa.N = N;
    int px = (65536 > N ? 65536 : N);
    prep_kernel<<<dim3((px + 255) / 256, 6), 256, 0, stream>>>(pa, flags);

    int gmb = (N + 31) / 32;
    proj_mfma_kernel<<<dim3(gmb, 4), 256, 0, stream>>>(x, Wlt, Wrt, smalls, (unsigned short*)xl,
                                                       (unsigned short*)xr, N, flags);

    hist_kernel<<<(E + 255) / 256, 256, 0, stream>>>(ei, deg, flags, E, N);
    scanA_kernel<<<nb, 256, 0, stream>>>(deg, part, N);
    scanB_kernel<<<1, 1024, 0, stream>>>(part, rowptr, nb, N);
    scanC_kernel<<<nb, 256, 0, stream>>>(deg, part, rowptr, cursor, N);
    scatter_kernel<<<(ET + 255) / 256, 256, 0, stream>>>(ei, cursor, srcs, flags, E, ET, N);

    agg_kernel<<<(N + 3) / 4, 256, 0, stream>>>(xl, xr, x, rowptr, srcs, smalls, N, flags);

    ffn1_mfma_kernel<<<gmb, 256, 0, stream>>>(hnrows, W1t, smalls, mid, N);
    ffn2_mfma_kernel<<<(N + 63) / 64, 256, 0, stream>>>(mid, hnrows, W2t, smalls, d_out, N, flags);
}